// Round 5
// baseline (53480.096 us; speedup 1.0000x reference)
//
#include <hip/hip_runtime.h>
#include <math.h>

// ============================================================================
// LARNN forward, MI355X — persistent single-kernel design.
// ALL-F32 BY NECESSITY: recurrence is chaotic (near-degenerate BN columns,
// 128 recurrent steps). f32 gives absmax 0.0625 vs threshold 0.3125; bf16
// anywhere gave 17.6 (decorrelated). Deterministic BN stats (no float
// atomics) for the same reason.
// Structure: 256 blocks x 512 threads, manual device-scope grid barrier,
// 6 phases per step. h never materialized: BN(hv) applied on load from stP.
// ============================================================================

#define T_  128
#define B_  256
#define F_  128
#define H_  512
#define W_  16
#define H4_ 2048
#define EPS_ 1e-5f
#define BH_ (B_*H_)
#define NBLK 256
#define NTHR 512

typedef __attribute__((ext_vector_type(4))) float f4;
typedef __attribute__((ext_vector_type(2))) float f2;

__device__ __forceinline__ float eluf(float x){ return x > 0.f ? x : expf(x) - 1.f; }
__device__ __forceinline__ float sigf(float x){ return 1.f / (1.f + expf(-x)); }

struct Params {
  const float *x, *W_ih, *b_ih, *W_hh, *Wq_in, *bq_in, *Wq, *bq, *Wk, *bk,
              *Wv, *bv, *Wo, *bo, *W_ac, *b_ac, *g_att, *be_att, *g_post, *be_post;
  float *out, *c, *q, *Qh, *ctx, *attp, *hv, *pre, *Kbuf, *Vbuf, *stA, *stP;
  unsigned *cnt, *gen;
};

// ---------------------------------------------------------------------------
// Device-scope grid barrier (sense = monotonically increasing generation).
// Winner resets cnt BEFORE releasing gen (release-store orders it).
// ---------------------------------------------------------------------------
__device__ __forceinline__ void gbar(unsigned* cnt, unsigned* gen, unsigned g) {
  __syncthreads();
  if (threadIdx.x == 0) {
    __threadfence();
    unsigned a = __hip_atomic_fetch_add(cnt, 1u, __ATOMIC_ACQ_REL, __HIP_MEMORY_SCOPE_AGENT);
    if (a == NBLK - 1) {
      __hip_atomic_store(cnt, 0u, __ATOMIC_RELAXED, __HIP_MEMORY_SCOPE_AGENT);
      __hip_atomic_store(gen, g, __ATOMIC_RELEASE, __HIP_MEMORY_SCOPE_AGENT);
    } else {
      while (__hip_atomic_load(gen, __ATOMIC_ACQUIRE, __HIP_MEMORY_SCOPE_AGENT) < g)
        __builtin_amdgcn_s_sleep(2);
    }
    __threadfence();
  }
  __syncthreads();
}

// BN scale/shift from single-partial stats stP[2][512] (gates output).
__device__ __forceinline__ void prepP(const float* stP, const float* gn, const float* be,
                                      float* scl, float* shf, int tid) {
  if (tid < H_) {
    float mu  = stP[tid] * (1.f / B_);
    float var = stP[H_ + tid] * (1.f / B_) - mu * mu;
    float sc  = rsqrtf(var + EPS_) * gn[tid];
    scl[tid] = sc; shf[tid] = be[tid] - mu * sc;
  }
}

// BN scale/shift from 4-way partial stats stA[4][2][512] (Wo GEMM output).
__device__ __forceinline__ void prepA(const float* stA, const float* gn, const float* be,
                                      float* scl, float* shf, int tid) {
  if (tid < H_) {
    float S  = stA[tid] + stA[1024 + tid] + stA[2048 + tid] + stA[3072 + tid];
    float S2 = stA[512 + tid] + stA[1536 + tid] + stA[2560 + tid] + stA[3584 + tid];
    float mu  = S * (1.f / B_);
    float var = S2 * (1.f / B_) - mu * mu;
    float sc  = rsqrtf(var + EPS_) * gn[tid];
    scl[tid] = sc; shf[tid] = be[tid] - mu * sc;
  }
}

// ---------------------------------------------------------------------------
// One 64x64 output tile, K-concat of up to 2 segments, 512 threads.
// Microtile 2x4 (ty=tid>>4 owns rows ty*2,ty*2+1; tx=tid&15 owns cols tx*4..+3).
// A staged row-major As[64][36]; B row-major Bs[32][68].
// nrm: apply scl/shf to A element (indexed by k) on load.
// ---------------------------------------------------------------------------
struct GJ {
  const float* A1; int lda1; const float* W1; int K1; int nrm1;
  const float* A2; int lda2; const float* W2; int K2; int nrm2;
  const float* b1; const float* b2; const float* addm;
  float* out; float* stats;
  int N; int m0; int n0; int doElu;
};

__device__ void gemm_tile(const GJ& J, int tid,
                          float (*As)[36], float (*Bs)[68],
                          const float* scl, const float* shf) {
  const int ty = tid >> 4, tx = tid & 15;
  const int arow = tid >> 3, akq = (tid & 7) * 4;
  const int bkk = tid >> 4, bnn = (tid & 15) * 4;
  float acc[2][4] = {{0.f,0.f,0.f,0.f},{0.f,0.f,0.f,0.f}};

  for (int s = 0; s < 2; ++s) {
    const float* A  = s ? J.A2 : J.A1;
    if (!A) break;
    const float* Wp = s ? J.W2 : J.W1;
    const int K   = s ? J.K2 : J.K1;
    const int lda = s ? J.lda2 : J.lda1;
    const int nrm = s ? J.nrm2 : J.nrm1;
    for (int kc = 0; kc < K; kc += 32) {
      __syncthreads();
      f4 av = *(const f4*)(A + (size_t)(J.m0 + arow) * lda + kc + akq);
      if (nrm) {
        #pragma unroll
        for (int i = 0; i < 4; ++i) av[i] = av[i] * scl[kc + akq + i] + shf[kc + akq + i];
      }
      *(f4*)&As[arow][akq] = av;
      *(f4*)&Bs[bkk][bnn] = *(const f4*)(Wp + (size_t)(kc + bkk) * J.N + J.n0 + bnn);
      __syncthreads();
      #pragma unroll
      for (int k = 0; k < 32; k += 2) {
        f2 a0 = *(const f2*)&As[ty * 2][k];
        f2 a1 = *(const f2*)&As[ty * 2 + 1][k];
        f4 b0 = *(const f4*)&Bs[k][tx * 4];
        f4 b1 = *(const f4*)&Bs[k + 1][tx * 4];
        #pragma unroll
        for (int j = 0; j < 4; ++j) {
          acc[0][j] = fmaf(a0[0], b0[j], acc[0][j]);
          acc[0][j] = fmaf(a0[1], b1[j], acc[0][j]);
          acc[1][j] = fmaf(a1[0], b0[j], acc[1][j]);
          acc[1][j] = fmaf(a1[1], b1[j], acc[1][j]);
        }
      }
    }
  }

  const int r0 = J.m0 + ty * 2, c0 = J.n0 + tx * 4;
  f4 bias = {0.f, 0.f, 0.f, 0.f};
  if (J.b1) {
    #pragma unroll
    for (int j = 0; j < 4; ++j) bias[j] += J.b1[c0 + j];
  }
  if (J.b2) {
    #pragma unroll
    for (int j = 0; j < 4; ++j) bias[j] += J.b2[c0 + j];
  }
  f4 v0, v1;
  #pragma unroll
  for (int j = 0; j < 4; ++j) { v0[j] = acc[0][j] + bias[j]; v1[j] = acc[1][j] + bias[j]; }
  if (J.addm) {
    v0 += *(const f4*)(J.addm + (size_t)r0 * J.N + c0);
    v1 += *(const f4*)(J.addm + (size_t)(r0 + 1) * J.N + c0);
  }
  if (J.doElu) {
    #pragma unroll
    for (int j = 0; j < 4; ++j) { v0[j] = eluf(v0[j]); v1[j] = eluf(v1[j]); }
  }
  *(f4*)(J.out + (size_t)r0 * J.N + c0) = v0;
  *(f4*)(J.out + (size_t)(r0 + 1) * J.N + c0) = v1;

  if (J.stats) {   // deterministic per-64-row-m-tile column partials
    float* Af = &As[0][0];
    float* Bf = &Bs[0][0];
    __syncthreads();
    #pragma unroll
    for (int j = 0; j < 4; ++j) {
      Af[ty * 64 + tx * 4 + j] = v0[j] + v1[j];
      Bf[ty * 64 + tx * 4 + j] = v0[j] * v0[j] + v1[j] * v1[j];
    }
    __syncthreads();
    if (tid < 64) {
      float S = 0.f, S2 = 0.f;
      #pragma unroll
      for (int yy = 0; yy < 32; ++yy) { S += Af[yy * 64 + tid]; S2 += Bf[yy * 64 + tid]; }
      const int tm = J.m0 >> 6;
      J.stats[tm * 1024 + J.n0 + tid] = S;
      J.stats[tm * 1024 + 512 + J.n0 + tid] = S2;
    }
  }
}

__global__ __launch_bounds__(NTHR) void larnn(Params P) {
  __shared__ float As[64][36];
  __shared__ float Bs[32][68];
  __shared__ float scl[H_], shf[H_];
  __shared__ float Qs[H_];
  __shared__ float sc_[8][16], aw_[8][16];

  const int bid = blockIdx.x, tid = threadIdx.x;
  unsigned g = 0;

  for (int t = 0; t < T_; ++t) {
    const float* xt = P.x + (size_t)t * B_ * F_;
    const int slot = (t - 1) & 15;

    // =========== P1: q | K-ring | V-ring | preA | out[t-1] ===========
    if (bid < 32) {
      if (t > 0) prepP(P.stP, P.g_post, P.be_post, scl, shf, tid);
      GJ J = {}; J.A1 = xt; J.lda1 = F_; J.W1 = P.Wq_in; J.K1 = F_;
      if (t > 0) { J.A2 = P.hv; J.lda2 = H_; J.W2 = P.Wq_in + (size_t)F_ * H_; J.K2 = H_; J.nrm2 = 1; }
      J.b1 = P.bq_in; J.out = P.q; J.N = H_;
      J.m0 = (bid >> 3) * 64; J.n0 = (bid & 7) * 64; J.doElu = 1;
      gemm_tile(J, tid, As, Bs, scl, shf);
    } else if (bid < 64) {
      GJ J = {}; J.A1 = P.c; J.lda1 = H_; J.W1 = P.Wk; J.K1 = H_;
      J.b1 = P.bk; J.out = P.Kbuf + (size_t)slot * BH_; J.N = H_;
      J.m0 = ((bid - 32) >> 3) * 64; J.n0 = ((bid - 32) & 7) * 64; J.doElu = 1;
      gemm_tile(J, tid, As, Bs, scl, shf);
    } else if (bid < 96) {
      GJ J = {}; J.A1 = P.c; J.lda1 = H_; J.W1 = P.Wv; J.K1 = H_;
      J.b1 = P.bv; J.out = P.Vbuf + (size_t)slot * BH_; J.N = H_;
      J.m0 = ((bid - 64) >> 3) * 64; J.n0 = ((bid - 64) & 7) * 64; J.doElu = 1;
      gemm_tile(J, tid, As, Bs, scl, shf);
    } else if (bid < 224) {
      if (t > 0) prepP(P.stP, P.g_post, P.be_post, scl, shf, tid);
      const int ix = bid - 96;
      GJ J = {}; J.A1 = xt; J.lda1 = F_; J.W1 = P.W_ih; J.K1 = F_;
      if (t > 0) { J.A2 = P.hv; J.lda2 = H_; J.W2 = P.W_hh; J.K2 = H_; J.nrm2 = 1; }
      J.b1 = P.b_ih; J.b2 = P.b_ac; J.out = P.pre; J.N = H4_;
      J.m0 = (ix >> 5) * 64; J.n0 = (ix & 31) * 64;
      gemm_tile(J, tid, As, Bs, scl, shf);
    } else if (t > 0) {
      prepP(P.stP, P.g_post, P.be_post, scl, shf, tid);
      __syncthreads();
      const int rb0 = (bid - 224) * 8;
      for (int idx = tid; idx < 1024; idx += NTHR) {
        int r = rb0 + (idx >> 7), cc = (idx & 127) * 4;
        f4 hvv = *(const f4*)(P.hv + (size_t)r * H_ + cc);
        f4 v;
        #pragma unroll
        for (int i = 0; i < 4; ++i) v[i] = hvv[i] * scl[cc + i] + shf[cc + i];
        *(f4*)(P.out + (size_t)(t - 1) * BH_ + (size_t)r * H_ + cc) = v;
      }
    }
    gbar(P.cnt, P.gen, ++g);

    // =========== P2: Qh = q@Wq + bq ===========
    if (bid < 32) {
      GJ J = {}; J.A1 = P.q; J.lda1 = H_; J.W1 = P.Wq; J.K1 = H_;
      J.b1 = P.bq; J.out = P.Qh; J.N = H_;
      J.m0 = (bid >> 3) * 64; J.n0 = (bid & 7) * 64;
      gemm_tile(J, tid, As, Bs, scl, shf);
    }
    gbar(P.cnt, P.gen, ++g);

    // =========== P3: attention (1 batch row / block) ===========
    {
      const int b = bid;
      const int nv = (t + 1 < W_) ? t + 1 : W_;
      if (tid < 128) *(f4*)&Qs[tid * 4] = *(const f4*)(P.Qh + (size_t)b * H_ + tid * 4);
      __syncthreads();
      {
        const int p = tid >> 2, l4 = tid & 3;
        const int hh = p >> 4, w = p & 15;
        if (w < nv) {
          const int sl = (t - 1 - w) & 15;
          const float* kp = P.Kbuf + ((size_t)sl * B_ + b) * H_ + hh * 64 + l4 * 16;
          const float* qp = Qs + hh * 64 + l4 * 16;
          float s = 0.f;
          #pragma unroll
          for (int d = 0; d < 16; d += 4) {
            f4 kv = *(const f4*)(kp + d);
            f4 qv = *(const f4*)(qp + d);
            s = fmaf(kv[0], qv[0], fmaf(kv[1], qv[1], fmaf(kv[2], qv[2], fmaf(kv[3], qv[3], s))));
          }
          s += __shfl_xor(s, 1); s += __shfl_xor(s, 2);
          if (l4 == 0) sc_[hh][w] = s * 0.125f;
        }
      }
      __syncthreads();
      if (tid < 8) {
        float mx = -1e30f;
        for (int w = 0; w < nv; ++w) mx = fmaxf(mx, sc_[tid][w]);
        float ss = 0.f;
        for (int w = 0; w < nv; ++w) { float e = expf(sc_[tid][w] - mx); aw_[tid][w] = e; ss += e; }
        float inv = 1.f / ss;
        for (int w = 0; w < nv; ++w) aw_[tid][w] *= inv;
      }
      __syncthreads();
      {
        const int j = tid, hh = j >> 6;
        float o = 0.f;
        for (int w = 0; w < nv; ++w) {
          const int sl = (t - 1 - w) & 15;
          o = fmaf(aw_[hh][w], P.Vbuf[((size_t)sl * B_ + b) * H_ + j], o);
        }
        P.ctx[(size_t)b * H_ + j] = o;
      }
    }
    gbar(P.cnt, P.gen, ++g);

    // =========== P4: attp = elu(ctx@Wo + bo) + BN partials ===========
    if (bid < 32) {
      GJ J = {}; J.A1 = P.ctx; J.lda1 = H_; J.W1 = P.Wo; J.K1 = H_;
      J.b1 = P.bo; J.out = P.attp; J.stats = P.stA; J.N = H_;
      J.m0 = (bid >> 3) * 64; J.n0 = (bid & 7) * 64; J.doElu = 1;
      gemm_tile(J, tid, As, Bs, scl, shf);
    }
    gbar(P.cnt, P.gen, ++g);

    // =========== P5: pre += BN(attp)@W_ac ===========
    if (bid < 128) {
      prepA(P.stA, P.g_att, P.be_att, scl, shf, tid);
      GJ J = {}; J.A1 = P.attp; J.lda1 = H_; J.W1 = P.W_ac; J.K1 = H_; J.nrm1 = 1;
      J.addm = P.pre; J.out = P.pre; J.N = H4_;
      J.m0 = (bid >> 5) * 64; J.n0 = (bid & 31) * 64;
      gemm_tile(J, tid, As, Bs, scl, shf);
    }
    gbar(P.cnt, P.gen, ++g);

    // =========== P6: gates + c/hv + BN-post stats ===========
    if (bid < 64) {
      f4* rS = (f4*)&As[0][0];   // [2][256]
      f4* rQ = (f4*)&Bs[0][0];
      const int sub = tid & 1, r = tid >> 1;
      const int c4 = bid * 8 + sub * 4;
      const size_t rb = (size_t)r * H4_;
      f4 p0 = *(const f4*)(P.pre + rb + c4);
      f4 pf = *(const f4*)(P.pre + rb + c4 + 512);
      f4 pi = *(const f4*)(P.pre + rb + c4 + 1024);
      f4 po = *(const f4*)(P.pre + rb + c4 + 1536);
      const size_t ci = (size_t)r * H_ + c4;
      f4 cold = *(const f4*)(P.c + ci);
      f4 cn, hvv;
      #pragma unroll
      for (int i = 0; i < 4; ++i) {
        float iv = tanhf(p0[i]);
        float fg = sigf(pf[i]), ig = sigf(pi[i]), og = sigf(po[i]);
        cn[i] = iv * ig + cold[i] * fg;
        hvv[i] = og * eluf(cn[i]);
      }
      *(f4*)(P.c + ci) = cn;
      *(f4*)(P.hv + ci) = hvv;
      rS[sub * 256 + r] = hvv;
      rQ[sub * 256 + r] = hvv * hvv;
      __syncthreads();
      for (int s2 = 128; s2 > 0; s2 >>= 1) {
        if (r < s2) {
          rS[sub * 256 + r] += rS[sub * 256 + r + s2];
          rQ[sub * 256 + r] += rQ[sub * 256 + r + s2];
        }
        __syncthreads();
      }
      if (r == 0) {
        f4 S = rS[sub * 256], Q2 = rQ[sub * 256];
        #pragma unroll
        for (int i = 0; i < 4; ++i) { P.stP[c4 + i] = S[i]; P.stP[512 + c4 + i] = Q2[i]; }
      }
    }
    gbar(P.cnt, P.gen, ++g);
  }

  // =========== final out-copy for t = 127 ===========
  if (bid >= 224) {
    prepP(P.stP, P.g_post, P.be_post, scl, shf, tid);
    __syncthreads();
    const int rb0 = (bid - 224) * 8;
    for (int idx = tid; idx < 1024; idx += NTHR) {
      int r = rb0 + (idx >> 7), cc = (idx & 127) * 4;
      f4 hvv = *(const f4*)(P.hv + (size_t)r * H_ + cc);
      f4 v;
      #pragma unroll
      for (int i = 0; i < 4; ++i) v[i] = hvv[i] * scl[cc + i] + shf[cc + i];
      *(f4*)(P.out + (size_t)127 * BH_ + (size_t)r * H_ + cc) = v;
    }
  }
}

__global__ __launch_bounds__(256) void pinit(float* c, unsigned* cnt, unsigned* gen) {
  const int i = blockIdx.x * 256 + threadIdx.x;
  if (i < BH_) c[i] = 0.f;
  if (i == 0) { *cnt = 0u; *gen = 0u; }
}

extern "C" void kernel_launch(void* const* d_in, const int* in_sizes, int n_in,
                              void* d_out, int out_size, void* d_ws, size_t ws_size,
                              hipStream_t stream) {
  Params P;
  P.x      = (const float*)d_in[0];
  P.W_ih   = (const float*)d_in[1];
  P.b_ih   = (const float*)d_in[2];
  P.W_hh   = (const float*)d_in[3];
  P.Wq_in  = (const float*)d_in[4];
  P.bq_in  = (const float*)d_in[5];
  P.Wq     = (const float*)d_in[6];
  P.bq     = (const float*)d_in[7];
  P.Wk     = (const float*)d_in[8];
  P.bk     = (const float*)d_in[9];
  P.Wv     = (const float*)d_in[10];
  P.bv     = (const float*)d_in[11];
  P.Wo     = (const float*)d_in[12];
  P.bo     = (const float*)d_in[13];
  P.W_ac   = (const float*)d_in[14];
  P.b_ac   = (const float*)d_in[15];
  P.g_att  = (const float*)d_in[16];
  P.be_att = (const float*)d_in[17];
  P.g_post = (const float*)d_in[18];
  P.be_post= (const float*)d_in[19];
  P.out    = (float*)d_out;

  P.cnt = (unsigned*)d_ws;
  P.gen = P.cnt + 64;                       // separate cacheline
  float* fb = (float*)d_ws + 128;
  P.c    = fb;                 fb += BH_;
  P.q    = fb;                 fb += BH_;
  P.Qh   = fb;                 fb += BH_;
  P.ctx  = fb;                 fb += BH_;
  P.attp = fb;                 fb += BH_;
  P.hv   = fb;                 fb += BH_;
  P.pre  = fb;                 fb += (size_t)B_ * H4_;
  P.Kbuf = fb;                 fb += (size_t)W_ * BH_;
  P.Vbuf = fb;                 fb += (size_t)W_ * BH_;
  P.stA  = fb;                 fb += 4096;
  P.stP  = fb;                 fb += 1024;

  pinit<<<(BH_ + 255) / 256, 256, 0, stream>>>(P.c, P.cnt, P.gen);
  larnn<<<NBLK, NTHR, 0, stream>>>(P);
}